// Round 1
// baseline (1070.303 us; speedup 1.0000x reference)
//
#include <hip/hip_runtime.h>
#include <math.h>

#define BB 16
#define TT 1024
#define SS 2048
#define CC 256
#define EE 256
#define NSUB 103        // (SS-1)/STRIDE + 1
#define MAXS 20
#define STRIDE_ 20

static constexpr float RSQRT2  = 0.70710678118654752440f;   // sqrt(0.5)
static constexpr float SQRT_S  = 45.25483399593904f;        // s*sqrt(1/s) = sqrt(2048)
static constexpr float GNORM   = 0.13298076013381093f;      // 1/(sqrt(2*pi)*3)
static constexpr float INV2S2  = 0.055555555555555555f;     // 1/(2*sigma^2)

__device__ __forceinline__ float wave_sum(float v) {
    #pragma unroll
    for (int o = 32; o; o >>= 1) v += __shfl_down(v, o);
    return v;
}
__device__ __forceinline__ float wave_max(float v) {
    #pragma unroll
    for (int o = 32; o; o >>= 1) v = fmaxf(v, __shfl_down(v, o));
    return v;
}

// ---------------------------------------------------------------------------
// NT GEMM (M=B*T=16384, N=256, K=256), C[m,n] = (sum_k A[m,k]*Bw[n,k] + bias[n]
//                                               + add[m*256+n]) * RSQRT2
// Used for GEMM1 (h) and GEMM4 (final out).
// ---------------------------------------------------------------------------
__global__ __launch_bounds__(256) void k_gemm_nt(
    const float* __restrict__ A, const float* __restrict__ Bw,
    const float* __restrict__ bias, const float* __restrict__ add,
    float* __restrict__ out)
{
    __shared__ float As[16][64];
    __shared__ float Bs[16][64];
    const int m0 = blockIdx.x * 64;
    const int n0 = blockIdx.y * 64;
    const int tid = threadIdx.x;
    const int tx = tid & 15, ty = tid >> 4;
    float acc[4][4] = {};
    for (int k0 = 0; k0 < 256; k0 += 16) {
        const int kk = tid & 15, rr = tid >> 4;
        #pragma unroll
        for (int r = 0; r < 4; ++r)
            As[kk][rr + 16 * r] = A[(size_t)(m0 + rr + 16 * r) * 256 + k0 + kk];
        #pragma unroll
        for (int r = 0; r < 4; ++r)
            Bs[kk][rr + 16 * r] = Bw[(size_t)(n0 + rr + 16 * r) * 256 + k0 + kk];
        __syncthreads();
        #pragma unroll
        for (int k = 0; k < 16; ++k) {
            const float4 av = *reinterpret_cast<const float4*>(&As[k][ty << 2]);
            const float4 bv = *reinterpret_cast<const float4*>(&Bs[k][tx << 2]);
            const float a4[4] = {av.x, av.y, av.z, av.w};
            const float b4[4] = {bv.x, bv.y, bv.z, bv.w};
            #pragma unroll
            for (int i = 0; i < 4; ++i)
                #pragma unroll
                for (int j = 0; j < 4; ++j)
                    acc[i][j] += a4[i] * b4[j];
        }
        __syncthreads();
    }
    const float4 bi = *reinterpret_cast<const float4*>(&bias[n0 + (tx << 2)]);
    const float b4[4] = {bi.x, bi.y, bi.z, bi.w};
    #pragma unroll
    for (int i = 0; i < 4; ++i) {
        const int m = m0 + (ty << 2) + i;
        const float4 ad = *reinterpret_cast<const float4*>(&add[(size_t)m * 256 + n0 + (tx << 2)]);
        float4 o;
        o.x = (acc[i][0] + b4[0] + ad.x) * RSQRT2;
        o.y = (acc[i][1] + b4[1] + ad.y) * RSQRT2;
        o.z = (acc[i][2] + b4[2] + ad.z) * RSQRT2;
        o.w = (acc[i][3] + b4[3] + ad.w) * RSQRT2;
        *reinterpret_cast<float4*>(&out[(size_t)m * 256 + n0 + (tx << 2)]) = o;
    }
}

// ---------------------------------------------------------------------------
// Batched NN GEMM: per batch b (blockIdx.z), M=T=1024 rows,
// C[m,n] = scale * sum_k A[m,k]*Bm[k,n].  Used for GEMM2 (scores) and GEMM3.
// ---------------------------------------------------------------------------
__global__ __launch_bounds__(256) void k_gemm_nn(
    const float* __restrict__ Abase, const float* __restrict__ Bbase,
    float* __restrict__ Obase, int K, int Nn, float scale)
{
    const int b = blockIdx.z;
    const float* A  = Abase + (size_t)b * TT * K;
    const float* Bm = Bbase + (size_t)b * K * Nn;
    float* O        = Obase + (size_t)b * TT * Nn;
    __shared__ float As[16][64];
    __shared__ float Bs[16][64];
    const int m0 = blockIdx.x * 64;
    const int n0 = blockIdx.y * 64;
    const int tid = threadIdx.x;
    const int tx = tid & 15, ty = tid >> 4;
    float acc[4][4] = {};
    for (int k0 = 0; k0 < K; k0 += 16) {
        {
            const int kk = tid & 15, rr = tid >> 4;
            #pragma unroll
            for (int r = 0; r < 4; ++r)
                As[kk][rr + 16 * r] = A[(size_t)(m0 + rr + 16 * r) * K + k0 + kk];
        }
        {
            const int nn = tid & 63, kk2 = tid >> 6;   // kk2 in [0,4)
            #pragma unroll
            for (int r = 0; r < 4; ++r)
                Bs[kk2 + 4 * r][nn] = Bm[(size_t)(k0 + kk2 + 4 * r) * Nn + n0 + nn];
        }
        __syncthreads();
        #pragma unroll
        for (int k = 0; k < 16; ++k) {
            const float4 av = *reinterpret_cast<const float4*>(&As[k][ty << 2]);
            const float4 bv = *reinterpret_cast<const float4*>(&Bs[k][tx << 2]);
            const float a4[4] = {av.x, av.y, av.z, av.w};
            const float b4[4] = {bv.x, bv.y, bv.z, bv.w};
            #pragma unroll
            for (int i = 0; i < 4; ++i)
                #pragma unroll
                for (int j = 0; j < 4; ++j)
                    acc[i][j] += a4[i] * b4[j];
        }
        __syncthreads();
    }
    #pragma unroll
    for (int i = 0; i < 4; ++i) {
        const int m = m0 + (ty << 2) + i;
        float4 o;
        o.x = acc[i][0] * scale; o.y = acc[i][1] * scale;
        o.z = acc[i][2] * scale; o.w = acc[i][3] * scale;
        *reinterpret_cast<float4*>(&O[(size_t)m * Nn + n0 + (tx << 2)]) = o;
    }
}

// Row softmax over S=2048, in place. One block (256 thr) per row of B*T.
__global__ __launch_bounds__(256) void k_softmax(float* __restrict__ attn)
{
    float* p = attn + (size_t)blockIdx.x * SS;
    const int tid = threadIdx.x;
    __shared__ float w[4];
    float v[8];
    float mx = -INFINITY;
    #pragma unroll
    for (int i = 0; i < 8; ++i) { v[i] = p[tid + (i << 8)]; mx = fmaxf(mx, v[i]); }
    float wm = wave_max(mx);
    if ((tid & 63) == 0) w[tid >> 6] = wm;
    __syncthreads();
    const float m = fmaxf(fmaxf(w[0], w[1]), fmaxf(w[2], w[3]));
    float s = 0.f;
    #pragma unroll
    for (int i = 0; i < 8; ++i) { v[i] = expf(v[i] - m); s += v[i]; }
    __syncthreads();
    float wsv = wave_sum(s);
    if ((tid & 63) == 0) w[tid >> 6] = wsv;
    __syncthreads();
    const float inv = 1.0f / (w[0] + w[1] + w[2] + w[3]);
    #pragma unroll
    for (int i = 0; i < 8; ++i) p[tid + (i << 8)] = v[i] * inv;
}

// x_mean[b,s] = mean_t attn[b,t,s].  grid (S/256, B)
__global__ __launch_bounds__(256) void k_xmean(const float* __restrict__ attn,
                                               float* __restrict__ xmean)
{
    const int b = blockIdx.y;
    const int s = blockIdx.x * 256 + threadIdx.x;
    const float* p = attn + (size_t)b * TT * SS + s;
    float acc = 0.f;
    #pragma unroll 8
    for (int t = 0; t < TT; ++t) acc += p[(size_t)t * SS];
    xmean[(size_t)b * SS + s] = acc * (1.0f / TT);
}

// ns[b,n,:] = enc_values[b, n*STRIDE, :]/||.||;  aa[b,n] = xmean[b, n*STRIDE]
__global__ __launch_bounds__(256) void k_ns(const float* __restrict__ ev,
                                            const float* __restrict__ xmean,
                                            float* __restrict__ ns, float* __restrict__ aa)
{
    const int n = blockIdx.x, b = blockIdx.y;
    const int tid = threadIdx.x;
    const float* rowp = ev + ((size_t)b * SS + (size_t)n * STRIDE_) * EE;
    const float v = rowp[tid];
    __shared__ float w[4];
    float r = wave_sum(v * v);
    if ((tid & 63) == 0) w[tid >> 6] = r;
    __syncthreads();
    const float nrm = sqrtf(w[0] + w[1] + w[2] + w[3]);
    ns[((size_t)b * NSUB + n) * EE + tid] = v / nrm;
    if (tid == 0) aa[b * NSUB + n] = xmean[(size_t)b * SS + n * STRIDE_];
}

// L[b,i,j] = (aa_i*aa_j) * dot(ns_i, ns_j).  grid (N, B), 128 thr
__global__ __launch_bounds__(128) void k_L(const float* __restrict__ ns,
                                           const float* __restrict__ aa,
                                           float* __restrict__ Lm)
{
    const int i = blockIdx.x, b = blockIdx.y;
    const int tid = threadIdx.x;
    __shared__ float nsi[EE];
    nsi[tid]       = ns[((size_t)b * NSUB + i) * EE + tid];
    nsi[tid + 128] = ns[((size_t)b * NSUB + i) * EE + tid + 128];
    __syncthreads();
    const float ai = aa[b * NSUB + i];
    for (int j = tid; j < NSUB; j += 128) {
        const float* rj = ns + ((size_t)b * NSUB + j) * EE;
        float d = 0.f;
        #pragma unroll 4
        for (int e = 0; e < EE; ++e) d += nsi[e] * rj[e];
        Lm[((size_t)b * NSUB + i) * NSUB + j] = d * ai * aa[b * NSUB + j];
    }
}

// Greedy MAP DPP (Cholesky) — one block (128 thr = 2 waves) per batch.
__global__ __launch_bounds__(128) void k_bfgm(const float* __restrict__ Lm,
                                              float* __restrict__ mu)
{
    const int b = blockIdx.x;
    const int tid = threadIdx.x;
    const float* L = Lm + (size_t)b * NSUB * NSUB;
    __shared__ float D[128], mask[128], Cm[128][MAXS], cj[MAXS];
    __shared__ float rv[2];
    __shared__ int   ri[2];
    __shared__ int   Jsh;
    const bool act = tid < NSUB;
    D[tid]    = act ? L[(size_t)tid * NSUB + tid] : 0.0f;
    mask[tid] = act ? 1.0f : 0.0f;
    #pragma unroll
    for (int k = 0; k < MAXS; ++k) Cm[tid][k] = 0.0f;
    __syncthreads();

    auto argmax_step = [&](int t) {
        // key = log(D*mask); NaN acts as +inf (numpy argmax semantics), first-index ties
        float key = act ? logf(D[tid] * mask[tid]) : -INFINITY;
        if (isnan(key)) key = INFINITY;
        float v = key; int idx = tid;
        #pragma unroll
        for (int o = 32; o; o >>= 1) {
            float ov = __shfl_down(v, o); int oi = __shfl_down(idx, o);
            if (ov > v || (ov == v && oi < idx)) { v = ov; idx = oi; }
        }
        if ((tid & 63) == 0) { rv[tid >> 6] = v; ri[tid >> 6] = idx; }
        __syncthreads();
        if (tid == 0) {
            const int J = (rv[1] > rv[0] || (rv[1] == rv[0] && ri[1] < ri[0])) ? ri[1] : ri[0];
            Jsh = J; mask[J] = 0.0f; mu[b * MAXS + t] = (float)J;
        }
        __syncthreads();
    };

    argmax_step(0);
    for (int t = 1; t < MAXS; ++t) {
        if (tid < MAXS) cj[tid] = Cm[Jsh][tid];
        __syncthreads();
        const int J = Jsh;
        const float dj = D[J];
        float e = 0.0f;
        if (act) {
            const float Ljn = L[(size_t)J * NSUB + tid];
            float cd = 0.f;
            #pragma unroll
            for (int k = 0; k < MAXS; ++k) cd += Cm[tid][k] * cj[k];
            e = (Ljn - cd) / dj * mask[tid];
        }
        Cm[tid][t] = e;
        D[tid] -= e * e;
        __syncthreads();
        argmax_step(t);
    }
}

// dist[b,s] = softmax_s( sum_m gauss(s - mu[b,m]) ).  grid B, 256 thr
__global__ __launch_bounds__(256) void k_dist(const float* __restrict__ mu,
                                              float* __restrict__ dist)
{
    const int b = blockIdx.x;
    const int tid = threadIdx.x;
    __shared__ float mus[MAXS];
    __shared__ float w[4];
    if (tid < MAXS) mus[tid] = mu[b * MAXS + tid];
    __syncthreads();
    float g[8];
    float mx = -INFINITY;
    #pragma unroll
    for (int i = 0; i < 8; ++i) {
        const float s = (float)(tid + (i << 8));
        float acc = 0.f;
        #pragma unroll
        for (int m = 0; m < MAXS; ++m) { const float z = s - mus[m]; acc += expf(-(z * z) * INV2S2); }
        g[i] = acc * GNORM;
        mx = fmaxf(mx, g[i]);
    }
    float wm = wave_max(mx);
    if ((tid & 63) == 0) w[tid >> 6] = wm;
    __syncthreads();
    const float m = fmaxf(fmaxf(w[0], w[1]), fmaxf(w[2], w[3]));
    float sum = 0.f;
    #pragma unroll
    for (int i = 0; i < 8; ++i) { g[i] = expf(g[i] - m); sum += g[i]; }
    __syncthreads();
    float wsv = wave_sum(sum);
    if ((tid & 63) == 0) w[tid >> 6] = wsv;
    __syncthreads();
    const float inv = 1.0f / (w[0] + w[1] + w[2] + w[3]);
    #pragma unroll
    for (int i = 0; i < 8; ++i) dist[(size_t)b * SS + tid + (i << 8)] = g[i] * inv;
}

// -kl = -sum_{b,s} xm*(log(xm) - dist).  Single block.
__global__ __launch_bounds__(256) void k_kl(const float* __restrict__ xmean,
                                            const float* __restrict__ dist,
                                            float* __restrict__ outkl)
{
    const int tid = threadIdx.x;
    float acc = 0.f;
    for (int i = tid; i < BB * SS; i += 256) {
        const float xm = xmean[i];
        acc += xm * (logf(xm) - dist[i]);
    }
    __shared__ float w[4];
    float wsv = wave_sum(acc);
    if ((tid & 63) == 0) w[tid >> 6] = wsv;
    __syncthreads();
    if (tid == 0) outkl[0] = -(w[0] + w[1] + w[2] + w[3]);
}

extern "C" void kernel_launch(void* const* d_in, const int* in_sizes, int n_in,
                              void* d_out, int out_size, void* d_ws, size_t ws_size,
                              hipStream_t stream)
{
    const float* x     = (const float*)d_in[0];   // (B,T,C)
    const float* te    = (const float*)d_in[1];   // (B,T,E)
    const float* keys  = (const float*)d_in[2];   // (B,E,S)
    const float* vals  = (const float*)d_in[3];   // (B,S,E)
    const float* W_in  = (const float*)d_in[4];   // (E,C)
    const float* b_in  = (const float*)d_in[5];   // (E)
    const float* W_out = (const float*)d_in[6];   // (C,E)
    const float* b_out = (const float*)d_in[7];   // (C)

    float* outp = (float*)d_out;                       // (B,T,C)
    float* attn = outp + (size_t)BB * TT * CC;         // (B,T,S)
    float* klp  = attn + (size_t)BB * TT * SS;         // scalar

    float* ws    = (float*)d_ws;
    float* mid   = ws;                                  // (B,T,E)
    float* xmean = mid   + (size_t)BB * TT * EE;        // (B,S)
    float* ns    = xmean + (size_t)BB * SS;             // (B,N,E)
    float* aa    = ns    + (size_t)BB * NSUB * EE;      // (B,N)
    float* Lm    = aa    + (size_t)BB * NSUB;           // (B,N,N)
    float* mu    = Lm    + (size_t)BB * NSUB * NSUB;    // (B,MAXS)
    float* dist  = mu    + (size_t)BB * MAXS;           // (B,S)

    float* h = outp;  // h (B,T,E) staged in the out region, overwritten by GEMM4

    // 1) h = (x @ W_in^T + b_in + te) * sqrt(.5)
    k_gemm_nt<<<dim3(256, 4), 256, 0, stream>>>(x, W_in, b_in, te, h);
    // 2) scores = h @ enc_keys  -> attn region
    k_gemm_nn<<<dim3(16, 32, 16), 256, 0, stream>>>(h, keys, attn, EE, SS, 1.0f);
    // 3) softmax rows (in place)
    k_softmax<<<BB * TT, 256, 0, stream>>>(attn);
    // 4) x_mean
    k_xmean<<<dim3(SS / 256, BB), 256, 0, stream>>>(attn, xmean);
    // 5) DPP inputs
    k_ns<<<dim3(NSUB, BB), 256, 0, stream>>>(vals, xmean, ns, aa);
    k_L<<<dim3(NSUB, BB), 128, 0, stream>>>(ns, aa, Lm);
    k_bfgm<<<BB, 128, 0, stream>>>(Lm, mu);
    k_dist<<<BB, 256, 0, stream>>>(mu, dist);
    k_kl<<<1, 256, 0, stream>>>(xmean, dist, klp);
    // 6) mid = (attn @ enc_values) * sqrt(S)
    k_gemm_nn<<<dim3(16, 4, 16), 256, 0, stream>>>(attn, vals, mid, SS, EE, SQRT_S);
    // 7) out = (mid @ W_out^T + b_out + x) * sqrt(.5)   (overwrites h)
    k_gemm_nt<<<dim3(256, 4), 256, 0, stream>>>(mid, W_out, b_out, x, outp);
}

// Round 2
// 640.066 us; speedup vs baseline: 1.6722x; 1.6722x over previous
//
#include <hip/hip_runtime.h>
#include <math.h>

#define BB 16
#define TT 1024
#define SS 2048
#define CC 256
#define EE 256
#define NSUB 103        // (SS-1)/STRIDE + 1
#define MAXS 20
#define STRIDE_ 20

static constexpr float RSQRT2  = 0.70710678118654752440f;   // sqrt(0.5)
static constexpr float SQRT_S  = 45.25483399593904f;        // s*sqrt(1/s) = sqrt(2048)
static constexpr float GNORM   = 0.13298076013381093f;      // 1/(sqrt(2*pi)*3)
static constexpr float INV2S2  = 0.055555555555555555f;     // 1/(2*sigma^2)

typedef __attribute__((ext_vector_type(8))) __bf16 bf16x8;
typedef __attribute__((ext_vector_type(4))) float  f32x4;

__device__ __forceinline__ float wave_sum(float v) {
    #pragma unroll
    for (int o = 32; o; o >>= 1) v += __shfl_down(v, o);
    return v;
}
__device__ __forceinline__ float wave_max(float v) {
    #pragma unroll
    for (int o = 32; o; o >>= 1) v = fmaxf(v, __shfl_down(v, o));
    return v;
}
__device__ __forceinline__ unsigned short f2bf(float f) {   // RNE
    unsigned int u = __float_as_uint(f);
    u = (u + 0x7FFFu + ((u >> 16) & 1u)) >> 16;
    return (unsigned short)u;
}
__device__ __forceinline__ float bf2f(unsigned short s) {
    return __uint_as_float(((unsigned int)s) << 16);
}

#define GLD_LDS16(g, l) __builtin_amdgcn_global_load_lds(                      \
    (const __attribute__((address_space(1))) void*)(g),                        \
    (__attribute__((address_space(3))) void*)(l), 16, 0, 0)

// ---------------------------------------------------------------------------
// fp32 NT GEMM (M=B*T=16384, N=256, K=256):
// C[m,n] = (sum_k A[m,k]*Bw[n,k] + bias[n] + add[m*256+n]) * RSQRT2
// Optionally also emits bf16 copy of C. Used for GEMM1 (h) and GEMM4 (out).
// ---------------------------------------------------------------------------
__global__ __launch_bounds__(256) void k_gemm_nt(
    const float* __restrict__ A, const float* __restrict__ Bw,
    const float* __restrict__ bias, const float* __restrict__ add,
    float* __restrict__ out, unsigned short* __restrict__ outb)
{
    __shared__ float As[16][64];
    __shared__ float Bs[16][64];
    const int m0 = blockIdx.x * 64;
    const int n0 = blockIdx.y * 64;
    const int tid = threadIdx.x;
    const int tx = tid & 15, ty = tid >> 4;
    float acc[4][4] = {};
    for (int k0 = 0; k0 < 256; k0 += 16) {
        const int kk = tid & 15, rr = tid >> 4;
        #pragma unroll
        for (int r = 0; r < 4; ++r)
            As[kk][rr + 16 * r] = A[(size_t)(m0 + rr + 16 * r) * 256 + k0 + kk];
        #pragma unroll
        for (int r = 0; r < 4; ++r)
            Bs[kk][rr + 16 * r] = Bw[(size_t)(n0 + rr + 16 * r) * 256 + k0 + kk];
        __syncthreads();
        #pragma unroll
        for (int k = 0; k < 16; ++k) {
            const float4 av = *reinterpret_cast<const float4*>(&As[k][ty << 2]);
            const float4 bv = *reinterpret_cast<const float4*>(&Bs[k][tx << 2]);
            const float a4[4] = {av.x, av.y, av.z, av.w};
            const float b4[4] = {bv.x, bv.y, bv.z, bv.w};
            #pragma unroll
            for (int i = 0; i < 4; ++i)
                #pragma unroll
                for (int j = 0; j < 4; ++j)
                    acc[i][j] += a4[i] * b4[j];
        }
        __syncthreads();
    }
    const float4 bi = *reinterpret_cast<const float4*>(&bias[n0 + (tx << 2)]);
    const float b4[4] = {bi.x, bi.y, bi.z, bi.w};
    #pragma unroll
    for (int i = 0; i < 4; ++i) {
        const int m = m0 + (ty << 2) + i;
        const float4 ad = *reinterpret_cast<const float4*>(&add[(size_t)m * 256 + n0 + (tx << 2)]);
        float4 o;
        o.x = (acc[i][0] + b4[0] + ad.x) * RSQRT2;
        o.y = (acc[i][1] + b4[1] + ad.y) * RSQRT2;
        o.z = (acc[i][2] + b4[2] + ad.z) * RSQRT2;
        o.w = (acc[i][3] + b4[3] + ad.w) * RSQRT2;
        *reinterpret_cast<float4*>(&out[(size_t)m * 256 + n0 + (tx << 2)]) = o;
        if (outb) {
            union { unsigned short u[4]; unsigned long long v; } pk;
            pk.u[0] = f2bf(o.x); pk.u[1] = f2bf(o.y);
            pk.u[2] = f2bf(o.z); pk.u[3] = f2bf(o.w);
            *reinterpret_cast<unsigned long long*>(&outb[(size_t)m * 256 + n0 + (tx << 2)]) = pk.v;
        }
    }
}

// ---------------------------------------------------------------------------
// fp32 [Bz][R][Cc] -> bf16 [Bz][Cc][R] transpose. grid (R/64, Cc/64, Bz), 256 thr
// ---------------------------------------------------------------------------
__global__ __launch_bounds__(256) void k_transpose_bf16(
    const float* __restrict__ in, unsigned short* __restrict__ out, int R, int Cc)
{
    __shared__ float t[64][65];
    const int b = blockIdx.z;
    const int r0 = blockIdx.x * 64, c0 = blockIdx.y * 64;
    const float* ip = in + (size_t)b * R * Cc;
    unsigned short* op = out + (size_t)b * R * Cc;
    const int tx = threadIdx.x & 63, ty = threadIdx.x >> 6;  // ty in [0,4)
    #pragma unroll
    for (int i = 0; i < 16; ++i)
        t[ty + 4 * i][tx] = ip[(size_t)(r0 + ty + 4 * i) * Cc + c0 + tx];
    __syncthreads();
    #pragma unroll
    for (int i = 0; i < 16; ++i)
        op[(size_t)(c0 + ty + 4 * i) * R + r0 + tx] = f2bf(t[tx][ty + 4 * i]);
}

// ---------------------------------------------------------------------------
// bf16 MFMA GEMM (m97 pattern): A [Bz][M][K] bf16 row-major,
// Bt [Bz][N][K] bf16 row-major (i.e. B transposed), O [Bz][M][N] fp32.
// O[m,n] = scale * sum_k A[m,k] * Bt[n,k].
// 128x128 tile, 4 waves, BK=32, global_load_lds(16B), 16x16x32 MFMA.
// ---------------------------------------------------------------------------
__global__ __launch_bounds__(256) void k_gemm_mfma(
    const unsigned short* __restrict__ Abase,
    const unsigned short* __restrict__ Btbase,
    float* __restrict__ Obase, int M, int Nn, int K, float scale)
{
    __shared__ unsigned short As[128 * 32];
    __shared__ unsigned short Bs[128 * 32];
    const int b  = blockIdx.z;
    const int m0 = blockIdx.x * 128;
    const int n0 = blockIdx.y * 128;
    const unsigned short* A  = Abase  + (size_t)b * M  * K;
    const unsigned short* Bt = Btbase + (size_t)b * Nn * K;
    float* O = Obase + (size_t)b * M * Nn;

    const int tid  = threadIdx.x;
    const int w    = tid >> 6;          // wave 0..3
    const int lane = tid & 63;
    const int wm   = w & 1, wn = w >> 1;
    const int sr   = lane >> 2;         // staging row within 16-row chunk
    const int sk   = (lane & 3) * 8;    // staging k offset (elements)

    // wave w stages A rows [w*32, w*32+32) and Bt rows [w*32, w*32+32)
    const unsigned short* ga0 = A  + (size_t)(m0 + w * 32 + sr) * K + sk;
    const unsigned short* ga1 = ga0 + (size_t)16 * K;
    const unsigned short* gb0 = Bt + (size_t)(n0 + w * 32 + sr) * K + sk;
    const unsigned short* gb1 = gb0 + (size_t)16 * K;
    unsigned short* la0 = As + w * 1024;        // + lane*8 elems implicit
    unsigned short* la1 = As + w * 1024 + 512;
    unsigned short* lb0 = Bs + w * 1024;
    unsigned short* lb1 = Bs + w * 1024 + 512;

    const int fr = lane & 15;           // m/n within a 16-tile
    const int q  = (lane >> 4) * 8;     // k offset of this lane's quad

    f32x4 acc[4][4];
    #pragma unroll
    for (int i = 0; i < 4; ++i)
        #pragma unroll
        for (int j = 0; j < 4; ++j)
            acc[i][j] = (f32x4){0.f, 0.f, 0.f, 0.f};

    for (int k0 = 0; k0 < K; k0 += 32) {
        GLD_LDS16(ga0, la0);
        GLD_LDS16(ga1, la1);
        GLD_LDS16(gb0, lb0);
        GLD_LDS16(gb1, lb1);
        ga0 += 32; ga1 += 32; gb0 += 32; gb1 += 32;
        __syncthreads();   // vmcnt(0) drain: staged data visible
        bf16x8 af[4], bfr[4];
        #pragma unroll
        for (int i = 0; i < 4; ++i) {
            af[i]  = *reinterpret_cast<const bf16x8*>(&As[(wm * 64 + i * 16 + fr) * 32 + q]);
            bfr[i] = *reinterpret_cast<const bf16x8*>(&Bs[(wn * 64 + i * 16 + fr) * 32 + q]);
        }
        #pragma unroll
        for (int i = 0; i < 4; ++i)
            #pragma unroll
            for (int j = 0; j < 4; ++j)
                acc[i][j] = __builtin_amdgcn_mfma_f32_16x16x32_bf16(af[i], bfr[j], acc[i][j], 0, 0, 0);
        __syncthreads();   // all ds_reads done before next overwrite
    }

    // C/D layout: col = lane&15, row = (lane>>4)*4 + reg   [m89-verified]
    const int rb = (lane >> 4) * 4;
    #pragma unroll
    for (int i = 0; i < 4; ++i)
        #pragma unroll
        for (int j = 0; j < 4; ++j)
            #pragma unroll
            for (int r2 = 0; r2 < 4; ++r2) {
                const int m = m0 + wm * 64 + i * 16 + rb + r2;
                const int n = n0 + wn * 64 + j * 16 + fr;
                O[(size_t)m * Nn + n] = acc[i][j][r2] * scale;
            }
}

// Row softmax over S=2048, in place; also emits bf16 copy. One block per row.
__global__ __launch_bounds__(256) void k_softmax(float* __restrict__ attn,
                                                 unsigned short* __restrict__ attnb)
{
    float* p = attn + (size_t)blockIdx.x * SS;
    unsigned short* pb = attnb + (size_t)blockIdx.x * SS;
    const int tid = threadIdx.x;
    __shared__ float w[4];
    float v[8];
    const float4 v0 = *reinterpret_cast<const float4*>(&p[tid * 8]);
    const float4 v1 = *reinterpret_cast<const float4*>(&p[tid * 8 + 4]);
    v[0] = v0.x; v[1] = v0.y; v[2] = v0.z; v[3] = v0.w;
    v[4] = v1.x; v[5] = v1.y; v[6] = v1.z; v[7] = v1.w;
    float mx = -INFINITY;
    #pragma unroll
    for (int i = 0; i < 8; ++i) mx = fmaxf(mx, v[i]);
    float wm = wave_max(mx);
    if ((tid & 63) == 0) w[tid >> 6] = wm;
    __syncthreads();
    const float m = fmaxf(fmaxf(w[0], w[1]), fmaxf(w[2], w[3]));
    float s = 0.f;
    #pragma unroll
    for (int i = 0; i < 8; ++i) { v[i] = expf(v[i] - m); s += v[i]; }
    __syncthreads();
    float wsv = wave_sum(s);
    if ((tid & 63) == 0) w[tid >> 6] = wsv;
    __syncthreads();
    const float inv = 1.0f / (w[0] + w[1] + w[2] + w[3]);
    float4 o0, o1;
    o0.x = v[0] * inv; o0.y = v[1] * inv; o0.z = v[2] * inv; o0.w = v[3] * inv;
    o1.x = v[4] * inv; o1.y = v[5] * inv; o1.z = v[6] * inv; o1.w = v[7] * inv;
    *reinterpret_cast<float4*>(&p[tid * 8])     = o0;
    *reinterpret_cast<float4*>(&p[tid * 8 + 4]) = o1;
    union { unsigned short u[8]; uint4 v4; } pk;
    pk.u[0] = f2bf(o0.x); pk.u[1] = f2bf(o0.y); pk.u[2] = f2bf(o0.z); pk.u[3] = f2bf(o0.w);
    pk.u[4] = f2bf(o1.x); pk.u[5] = f2bf(o1.y); pk.u[6] = f2bf(o1.z); pk.u[7] = f2bf(o1.w);
    *reinterpret_cast<uint4*>(&pb[tid * 8]) = pk.v4;
}

// x_mean[b,s] = mean_t attn[b,t,s], from bf16 copy. grid (S/256, B)
__global__ __launch_bounds__(256) void k_xmean(const unsigned short* __restrict__ attnb,
                                               float* __restrict__ xmean)
{
    const int b = blockIdx.y;
    const int s = blockIdx.x * 256 + threadIdx.x;
    const unsigned short* p = attnb + (size_t)b * TT * SS + s;
    float acc = 0.f;
    #pragma unroll 8
    for (int t = 0; t < TT; ++t) acc += bf2f(p[(size_t)t * SS]);
    xmean[(size_t)b * SS + s] = acc * (1.0f / TT);
}

// ns[b,n,:] = enc_values[b, n*STRIDE, :]/||.||;  aa[b,n] = xmean[b, n*STRIDE]
__global__ __launch_bounds__(256) void k_ns(const float* __restrict__ ev,
                                            const float* __restrict__ xmean,
                                            float* __restrict__ ns, float* __restrict__ aa)
{
    const int n = blockIdx.x, b = blockIdx.y;
    const int tid = threadIdx.x;
    const float* rowp = ev + ((size_t)b * SS + (size_t)n * STRIDE_) * EE;
    const float v = rowp[tid];
    __shared__ float w[4];
    float r = wave_sum(v * v);
    if ((tid & 63) == 0) w[tid >> 6] = r;
    __syncthreads();
    const float nrm = sqrtf(w[0] + w[1] + w[2] + w[3]);
    ns[((size_t)b * NSUB + n) * EE + tid] = v / nrm;
    if (tid == 0) aa[b * NSUB + n] = xmean[(size_t)b * SS + n * STRIDE_];
}

// L[b,i,j] = (aa_i*aa_j) * dot(ns_i, ns_j).  grid (N, B), 128 thr
__global__ __launch_bounds__(128) void k_L(const float* __restrict__ ns,
                                           const float* __restrict__ aa,
                                           float* __restrict__ Lm)
{
    const int i = blockIdx.x, b = blockIdx.y;
    const int tid = threadIdx.x;
    __shared__ float nsi[EE];
    nsi[tid]       = ns[((size_t)b * NSUB + i) * EE + tid];
    nsi[tid + 128] = ns[((size_t)b * NSUB + i) * EE + tid + 128];
    __syncthreads();
    const float ai = aa[b * NSUB + i];
    for (int j = tid; j < NSUB; j += 128) {
        const float* rj = ns + ((size_t)b * NSUB + j) * EE;
        float d = 0.f;
        #pragma unroll 4
        for (int e = 0; e < EE; ++e) d += nsi[e] * rj[e];
        Lm[((size_t)b * NSUB + i) * NSUB + j] = d * ai * aa[b * NSUB + j];
    }
}

// Greedy MAP DPP (Cholesky) — one block (128 thr = 2 waves) per batch.
__global__ __launch_bounds__(128) void k_bfgm(const float* __restrict__ Lm,
                                              float* __restrict__ mu)
{
    const int b = blockIdx.x;
    const int tid = threadIdx.x;
    const float* L = Lm + (size_t)b * NSUB * NSUB;
    __shared__ float D[128], mask[128], Cm[128][MAXS], cj[MAXS];
    __shared__ float rv[2];
    __shared__ int   ri[2];
    __shared__ int   Jsh;
    const bool act = tid < NSUB;
    D[tid]    = act ? L[(size_t)tid * NSUB + tid] : 0.0f;
    mask[tid] = act ? 1.0f : 0.0f;
    #pragma unroll
    for (int k = 0; k < MAXS; ++k) Cm[tid][k] = 0.0f;
    __syncthreads();

    auto argmax_step = [&](int t) {
        float key = act ? logf(D[tid] * mask[tid]) : -INFINITY;
        if (isnan(key)) key = INFINITY;   // numpy argmax: NaN wins
        float v = key; int idx = tid;
        #pragma unroll
        for (int o = 32; o; o >>= 1) {
            float ov = __shfl_down(v, o); int oi = __shfl_down(idx, o);
            if (ov > v || (ov == v && oi < idx)) { v = ov; idx = oi; }
        }
        if ((tid & 63) == 0) { rv[tid >> 6] = v; ri[tid >> 6] = idx; }
        __syncthreads();
        if (tid == 0) {
            const int J = (rv[1] > rv[0] || (rv[1] == rv[0] && ri[1] < ri[0])) ? ri[1] : ri[0];
            Jsh = J; mask[J] = 0.0f; mu[b * MAXS + t] = (float)J;
        }
        __syncthreads();
    };

    argmax_step(0);
    for (int t = 1; t < MAXS; ++t) {
        if (tid < MAXS) cj[tid] = Cm[Jsh][tid];
        __syncthreads();
        const int J = Jsh;
        const float dj = D[J];
        float e = 0.0f;
        if (act) {
            const float Ljn = L[(size_t)J * NSUB + tid];
            float cd = 0.f;
            #pragma unroll
            for (int k = 0; k < MAXS; ++k) cd += Cm[tid][k] * cj[k];
            e = (Ljn - cd) / dj * mask[tid];
        }
        Cm[tid][t] = e;
        D[tid] -= e * e;
        __syncthreads();
        argmax_step(t);
    }
}

// dist[b,s] = softmax_s( sum_m gauss(s - mu[b,m]) ).  grid B, 256 thr
__global__ __launch_bounds__(256) void k_dist(const float* __restrict__ mu,
                                              float* __restrict__ dist)
{
    const int b = blockIdx.x;
    const int tid = threadIdx.x;
    __shared__ float mus[MAXS];
    __shared__ float w[4];
    if (tid < MAXS) mus[tid] = mu[b * MAXS + tid];
    __syncthreads();
    float g[8];
    float mx = -INFINITY;
    #pragma unroll
    for (int i = 0; i < 8; ++i) {
        const float s = (float)(tid + (i << 8));
        float acc = 0.f;
        #pragma unroll
        for (int m = 0; m < MAXS; ++m) { const float z = s - mus[m]; acc += expf(-(z * z) * INV2S2); }
        g[i] = acc * GNORM;
        mx = fmaxf(mx, g[i]);
    }
    float wm = wave_max(mx);
    if ((tid & 63) == 0) w[tid >> 6] = wm;
    __syncthreads();
    const float m = fmaxf(fmaxf(w[0], w[1]), fmaxf(w[2], w[3]));
    float sum = 0.f;
    #pragma unroll
    for (int i = 0; i < 8; ++i) { g[i] = expf(g[i] - m); sum += g[i]; }
    __syncthreads();
    float wsv = wave_sum(sum);
    if ((tid & 63) == 0) w[tid >> 6] = wsv;
    __syncthreads();
    const float inv = 1.0f / (w[0] + w[1] + w[2] + w[3]);
    #pragma unroll
    for (int i = 0; i < 8; ++i) dist[(size_t)b * SS + tid + (i << 8)] = g[i] * inv;
}

// -kl = -sum_{b,s} xm*(log(xm) - dist).  Single block.
__global__ __launch_bounds__(256) void k_kl(const float* __restrict__ xmean,
                                            const float* __restrict__ dist,
                                            float* __restrict__ outkl)
{
    const int tid = threadIdx.x;
    float acc = 0.f;
    for (int i = tid; i < BB * SS; i += 256) {
        const float xm = xmean[i];
        acc += xm * (logf(xm) - dist[i]);
    }
    __shared__ float w[4];
    float wsv = wave_sum(acc);
    if ((tid & 63) == 0) w[tid >> 6] = wsv;
    __syncthreads();
    if (tid == 0) outkl[0] = -(w[0] + w[1] + w[2] + w[3]);
}

extern "C" void kernel_launch(void* const* d_in, const int* in_sizes, int n_in,
                              void* d_out, int out_size, void* d_ws, size_t ws_size,
                              hipStream_t stream)
{
    const float* x     = (const float*)d_in[0];   // (B,T,C)
    const float* te    = (const float*)d_in[1];   // (B,T,E)
    const float* keys  = (const float*)d_in[2];   // (B,E,S)
    const float* vals  = (const float*)d_in[3];   // (B,S,E)
    const float* W_in  = (const float*)d_in[4];   // (E,C)
    const float* b_in  = (const float*)d_in[5];   // (E)
    const float* W_out = (const float*)d_in[6];   // (C,E)
    const float* b_out = (const float*)d_in[7];   // (C)

    float* outp = (float*)d_out;                       // (B,T,C)
    float* attn = outp + (size_t)BB * TT * CC;         // (B,T,S) fp32
    float* klp  = attn + (size_t)BB * TT * SS;         // scalar

    // workspace layout (lifetime-overlaid):
    //   X region: [keysT bf16 16MB][h_bf16 8MB]  (both dead after GEMM2)
    //             then attnb bf16 67MB (written by softmax, read by xmean/GEMM3)
    unsigned short* X      = (unsigned short*)d_ws;
    unsigned short* keysT  = X;                                   // (B,S,E) bf16
    unsigned short* h_bf   = X + (size_t)BB * SS * EE;            // (B,T,E) bf16
    unsigned short* attnb  = X;                                   // (B,T,S) bf16
    unsigned short* valsT  = X + (size_t)BB * TT * SS;            // (B,E,S) bf16
    float* fws   = (float*)(valsT + (size_t)BB * SS * EE);
    float* mid   = fws;                                  // (B,T,E) f32
    float* xmean = mid   + (size_t)BB * TT * EE;         // (B,S)
    float* ns    = xmean + (size_t)BB * SS;              // (B,N,E)
    float* aa    = ns    + (size_t)BB * NSUB * EE;       // (B,N)
    float* Lm    = aa    + (size_t)BB * NSUB;            // (B,N,N)
    float* mu    = Lm    + (size_t)BB * NSUB * NSUB;     // (B,MAXS)
    float* dist  = mu    + (size_t)BB * MAXS;            // (B,S)

    float* h = outp;  // fp32 h staged in out region (overwritten by GEMM4)

    // 1) h = (x @ W_in^T + b_in + te) * sqrt(.5), + bf16 copy
    k_gemm_nt<<<dim3(256, 4), 256, 0, stream>>>(x, W_in, b_in, te, h, h_bf);
    // 2) keysT[b,s,e] = keys[b,e,s] (bf16)
    k_transpose_bf16<<<dim3(4, 32, BB), 256, 0, stream>>>(keys, keysT, EE, SS);
    // 3) scores = h @ keys  (MFMA, bf16) -> attn region
    k_gemm_mfma<<<dim3(8, 16, BB), 256, 0, stream>>>(h_bf, keysT, attn, TT, SS, EE, 1.0f);
    // 4) valsT[b,e,s] = vals[b,s,e] (bf16) — needed only for GEMM3
    k_transpose_bf16<<<dim3(32, 4, BB), 256, 0, stream>>>(vals, valsT, SS, EE);
    // 5) softmax rows in place + bf16 copy (overwrites keysT/h_bf — both dead)
    k_softmax<<<BB * TT, 256, 0, stream>>>(attn, attnb);
    // 6) x_mean from bf16 attn
    k_xmean<<<dim3(SS / 256, BB), 256, 0, stream>>>(attnb, xmean);
    // 7) DPP chain
    k_ns<<<dim3(NSUB, BB), 256, 0, stream>>>(vals, xmean, ns, aa);
    k_L<<<dim3(NSUB, BB), 128, 0, stream>>>(ns, aa, Lm);
    k_bfgm<<<BB, 128, 0, stream>>>(Lm, mu);
    k_dist<<<BB, 256, 0, stream>>>(mu, dist);
    k_kl<<<1, 256, 0, stream>>>(xmean, dist, klp);
    // 8) mid = (attn @ enc_values) * sqrt(S)  (MFMA, bf16)
    k_gemm_mfma<<<dim3(8, 2, BB), 256, 0, stream>>>(attnb, valsT, mid, TT, EE, SS, SQRT_S);
    // 9) out = (mid @ W_out^T + b_out + x) * sqrt(.5)
    k_gemm_nt<<<dim3(256, 4), 256, 0, stream>>>(mid, W_out, b_out, x, outp, (unsigned short*)nullptr);
}

// Round 3
// 576.616 us; speedup vs baseline: 1.8562x; 1.1100x over previous
//
#include <hip/hip_runtime.h>
#include <math.h>

#define BB 16
#define TT 1024
#define SS 2048
#define CC 256
#define EE 256
#define NSUB 103        // (SS-1)/STRIDE + 1
#define MAXS 20
#define STRIDE_ 20

static constexpr float RSQRT2  = 0.70710678118654752440f;   // sqrt(0.5)
static constexpr float SQRT_S  = 45.25483399593904f;        // s*sqrt(1/s) = sqrt(2048)
static constexpr float GNORM   = 0.13298076013381093f;      // 1/(sqrt(2*pi)*3)
static constexpr float INV2S2  = 0.055555555555555555f;     // 1/(2*sigma^2)

typedef __attribute__((ext_vector_type(8))) __bf16 bf16x8;
typedef __attribute__((ext_vector_type(4))) float  f32x4;

__device__ __forceinline__ float wave_sum(float v) {
    #pragma unroll
    for (int o = 32; o; o >>= 1) v += __shfl_down(v, o);
    return v;
}
__device__ __forceinline__ float wave_max(float v) {
    #pragma unroll
    for (int o = 32; o; o >>= 1) v = fmaxf(v, __shfl_down(v, o));
    return v;
}
__device__ __forceinline__ unsigned short f2bf(float f) {   // RNE
    unsigned int u = __float_as_uint(f);
    u = (u + 0x7FFFu + ((u >> 16) & 1u)) >> 16;
    return (unsigned short)u;
}
__device__ __forceinline__ float bf2f(unsigned short s) {
    return __uint_as_float(((unsigned int)s) << 16);
}

#define GLD_LDS16(g, l) __builtin_amdgcn_global_load_lds(                      \
    (const __attribute__((address_space(1))) void*)(g),                        \
    (__attribute__((address_space(3))) void*)(l), 16, 0, 0)

// fp32 -> bf16 cast, 4 elems/thread
__global__ __launch_bounds__(256) void k_cast_bf16(const float* __restrict__ in,
                                                   unsigned short* __restrict__ out, int n4)
{
    const int i = blockIdx.x * 256 + threadIdx.x;
    if (i < n4) {
        const float4 v = reinterpret_cast<const float4*>(in)[i];
        union { unsigned short u[4]; unsigned long long v8; } pk;
        pk.u[0] = f2bf(v.x); pk.u[1] = f2bf(v.y);
        pk.u[2] = f2bf(v.z); pk.u[3] = f2bf(v.w);
        reinterpret_cast<unsigned long long*>(out)[i] = pk.v8;
    }
}

// fp32 [Bz][R][Cc] -> bf16 [Bz][Cc][R] transpose. grid (R/64, Cc/64, Bz), 256 thr
__global__ __launch_bounds__(256) void k_transpose_bf16(
    const float* __restrict__ in, unsigned short* __restrict__ out, int R, int Cc)
{
    __shared__ float t[64][65];
    const int b = blockIdx.z;
    const int r0 = blockIdx.x * 64, c0 = blockIdx.y * 64;
    const float* ip = in + (size_t)b * R * Cc;
    unsigned short* op = out + (size_t)b * R * Cc;
    const int tx = threadIdx.x & 63, ty = threadIdx.x >> 6;  // ty in [0,4)
    #pragma unroll
    for (int i = 0; i < 16; ++i)
        t[ty + 4 * i][tx] = ip[(size_t)(r0 + ty + 4 * i) * Cc + c0 + tx];
    __syncthreads();
    #pragma unroll
    for (int i = 0; i < 16; ++i)
        op[(size_t)(c0 + ty + 4 * i) * R + r0 + tx] = f2bf(t[tx][ty + 4 * i]);
}

// ---------------------------------------------------------------------------
// bf16 MFMA GEMM (m97 pattern): A [Bz][M][K] bf16, Bt [Bz][N][K] bf16 (B^T),
// O[m,n] = epilogue(sum_k A[m,k]*Bt[n,k]).
// MODE 0: Of = acc*scale                     (GEMM2: scores, fp32)
// MODE 1: Of = (acc + bias[n] + add[m,n])*RSQRT2        (GEMM4: out, fp32)
// MODE 2: Ob = bf16((acc + bias[n] + add[m,n])*RSQRT2)  (GEMM1: h, bf16)
// MODE 3: Ob = bf16(acc*scale)               (GEMM3: mid, bf16)
// 128x128 tile, 4 waves, BK=32, global_load_lds(16B), 16x16x32 MFMA.
// ---------------------------------------------------------------------------
template<int MODE>
__global__ __launch_bounds__(256) void k_gemm_mfma(
    const unsigned short* __restrict__ Abase,
    const unsigned short* __restrict__ Btbase,
    const float* __restrict__ bias, const float* __restrict__ add,
    float* __restrict__ Obase, unsigned short* __restrict__ Obbase,
    int M, int Nn, int K, float scale)
{
    __shared__ unsigned short As[128 * 32];
    __shared__ unsigned short Bs[128 * 32];
    const int b  = blockIdx.z;
    const int m0 = blockIdx.x * 128;
    const int n0 = blockIdx.y * 128;
    const unsigned short* A  = Abase  + (size_t)b * M  * K;
    const unsigned short* Bt = Btbase + (size_t)b * Nn * K;

    const int tid  = threadIdx.x;
    const int w    = tid >> 6;          // wave 0..3
    const int lane = tid & 63;
    const int wm   = w & 1, wn = w >> 1;
    const int sr   = lane >> 2;         // staging row within 16-row chunk
    const int sk   = (lane & 3) * 8;    // staging k offset (elements)

    const unsigned short* ga0 = A  + (size_t)(m0 + w * 32 + sr) * K + sk;
    const unsigned short* ga1 = ga0 + (size_t)16 * K;
    const unsigned short* gb0 = Bt + (size_t)(n0 + w * 32 + sr) * K + sk;
    const unsigned short* gb1 = gb0 + (size_t)16 * K;
    unsigned short* la0 = As + w * 1024;
    unsigned short* la1 = As + w * 1024 + 512;
    unsigned short* lb0 = Bs + w * 1024;
    unsigned short* lb1 = Bs + w * 1024 + 512;

    const int fr = lane & 15;           // m/n within a 16-tile
    const int q  = (lane >> 4) * 8;     // k offset of this lane's quad

    f32x4 acc[4][4];
    #pragma unroll
    for (int i = 0; i < 4; ++i)
        #pragma unroll
        for (int j = 0; j < 4; ++j)
            acc[i][j] = (f32x4){0.f, 0.f, 0.f, 0.f};

    for (int k0 = 0; k0 < K; k0 += 32) {
        GLD_LDS16(ga0, la0);
        GLD_LDS16(ga1, la1);
        GLD_LDS16(gb0, lb0);
        GLD_LDS16(gb1, lb1);
        ga0 += 32; ga1 += 32; gb0 += 32; gb1 += 32;
        __syncthreads();
        bf16x8 af[4], bfr[4];
        #pragma unroll
        for (int i = 0; i < 4; ++i) {
            af[i]  = *reinterpret_cast<const bf16x8*>(&As[(wm * 64 + i * 16 + fr) * 32 + q]);
            bfr[i] = *reinterpret_cast<const bf16x8*>(&Bs[(wn * 64 + i * 16 + fr) * 32 + q]);
        }
        #pragma unroll
        for (int i = 0; i < 4; ++i)
            #pragma unroll
            for (int j = 0; j < 4; ++j)
                acc[i][j] = __builtin_amdgcn_mfma_f32_16x16x32_bf16(af[i], bfr[j], acc[i][j], 0, 0, 0);
        __syncthreads();
    }

    // C/D layout: col = lane&15, row = (lane>>4)*4 + reg   [m89-verified]
    float* Of = (MODE == 0 || MODE == 1) ? Obase + (size_t)b * M * Nn : nullptr;
    unsigned short* Ob = (MODE == 2 || MODE == 3) ? Obbase + (size_t)b * M * Nn : nullptr;
    const int rb = (lane >> 4) * 4;
    #pragma unroll
    for (int i = 0; i < 4; ++i)
        #pragma unroll
        for (int j = 0; j < 4; ++j) {
            const int n = n0 + wn * 64 + j * 16 + fr;
            #pragma unroll
            for (int r2 = 0; r2 < 4; ++r2) {
                const int m = m0 + wm * 64 + i * 16 + rb + r2;
                const size_t idx = (size_t)m * Nn + n;
                if (MODE == 0) {
                    Of[idx] = acc[i][j][r2] * scale;
                } else if (MODE == 1) {
                    Of[idx] = (acc[i][j][r2] + bias[n] + add[idx]) * RSQRT2;
                } else if (MODE == 2) {
                    Ob[idx] = f2bf((acc[i][j][r2] + bias[n] + add[idx]) * RSQRT2);
                } else {
                    Ob[idx] = f2bf(acc[i][j][r2] * scale);
                }
            }
        }
}

// Row softmax over S=2048, in place (fp32) + bf16 copy. One block per row.
__global__ __launch_bounds__(256) void k_softmax(float* __restrict__ attn,
                                                 unsigned short* __restrict__ attnb)
{
    float* p = attn + (size_t)blockIdx.x * SS;
    unsigned short* pb = attnb + (size_t)blockIdx.x * SS;
    const int tid = threadIdx.x;
    __shared__ float w[4];
    float v[8];
    const float4 v0 = *reinterpret_cast<const float4*>(&p[tid * 8]);
    const float4 v1 = *reinterpret_cast<const float4*>(&p[tid * 8 + 4]);
    v[0] = v0.x; v[1] = v0.y; v[2] = v0.z; v[3] = v0.w;
    v[4] = v1.x; v[5] = v1.y; v[6] = v1.z; v[7] = v1.w;
    float mx = -INFINITY;
    #pragma unroll
    for (int i = 0; i < 8; ++i) mx = fmaxf(mx, v[i]);
    float wm = wave_max(mx);
    if ((tid & 63) == 0) w[tid >> 6] = wm;
    __syncthreads();
    const float m = fmaxf(fmaxf(w[0], w[1]), fmaxf(w[2], w[3]));
    float s = 0.f;
    #pragma unroll
    for (int i = 0; i < 8; ++i) { v[i] = expf(v[i] - m); s += v[i]; }
    __syncthreads();
    float wsv = wave_sum(s);
    if ((tid & 63) == 0) w[tid >> 6] = wsv;
    __syncthreads();
    const float inv = 1.0f / (w[0] + w[1] + w[2] + w[3]);
    float4 o0, o1;
    o0.x = v[0] * inv; o0.y = v[1] * inv; o0.z = v[2] * inv; o0.w = v[3] * inv;
    o1.x = v[4] * inv; o1.y = v[5] * inv; o1.z = v[6] * inv; o1.w = v[7] * inv;
    *reinterpret_cast<float4*>(&p[tid * 8])     = o0;
    *reinterpret_cast<float4*>(&p[tid * 8 + 4]) = o1;
    union { unsigned short u[8]; uint4 v4; } pk;
    pk.u[0] = f2bf(o0.x); pk.u[1] = f2bf(o0.y); pk.u[2] = f2bf(o0.z); pk.u[3] = f2bf(o0.w);
    pk.u[4] = f2bf(o1.x); pk.u[5] = f2bf(o1.y); pk.u[6] = f2bf(o1.z); pk.u[7] = f2bf(o1.w);
    *reinterpret_cast<uint4*>(&pb[tid * 8]) = pk.v4;
}

// x_mean[b,s] = mean_t attn[b,t,s], from bf16 copy. grid (S/256, B)
__global__ __launch_bounds__(256) void k_xmean(const unsigned short* __restrict__ attnb,
                                               float* __restrict__ xmean)
{
    const int b = blockIdx.y;
    const int s = blockIdx.x * 256 + threadIdx.x;
    const unsigned short* p = attnb + (size_t)b * TT * SS + s;
    float acc = 0.f;
    #pragma unroll 8
    for (int t = 0; t < TT; ++t) acc += bf2f(p[(size_t)t * SS]);
    xmean[(size_t)b * SS + s] = acc * (1.0f / TT);
}

// ns[b,n,:] = enc_values[b, n*STRIDE, :]/||.||;  aa[b,n] = xmean[b, n*STRIDE]
__global__ __launch_bounds__(256) void k_ns(const float* __restrict__ ev,
                                            const float* __restrict__ xmean,
                                            float* __restrict__ ns, float* __restrict__ aa)
{
    const int n = blockIdx.x, b = blockIdx.y;
    const int tid = threadIdx.x;
    const float* rowp = ev + ((size_t)b * SS + (size_t)n * STRIDE_) * EE;
    const float v = rowp[tid];
    __shared__ float w[4];
    float r = wave_sum(v * v);
    if ((tid & 63) == 0) w[tid >> 6] = r;
    __syncthreads();
    const float nrm = sqrtf(w[0] + w[1] + w[2] + w[3]);
    ns[((size_t)b * NSUB + n) * EE + tid] = v / nrm;
    if (tid == 0) aa[b * NSUB + n] = xmean[(size_t)b * SS + n * STRIDE_];
}

// L[b,i,j] = (aa_i*aa_j) * dot(ns_i, ns_j).  grid (N, B), 128 thr
__global__ __launch_bounds__(128) void k_L(const float* __restrict__ ns,
                                           const float* __restrict__ aa,
                                           float* __restrict__ Lm)
{
    const int i = blockIdx.x, b = blockIdx.y;
    const int tid = threadIdx.x;
    __shared__ float nsi[EE];
    nsi[tid]       = ns[((size_t)b * NSUB + i) * EE + tid];
    nsi[tid + 128] = ns[((size_t)b * NSUB + i) * EE + tid + 128];
    __syncthreads();
    const float ai = aa[b * NSUB + i];
    for (int j = tid; j < NSUB; j += 128) {
        const float* rj = ns + ((size_t)b * NSUB + j) * EE;
        float d = 0.f;
        #pragma unroll 4
        for (int e = 0; e < EE; ++e) d += nsi[e] * rj[e];
        Lm[((size_t)b * NSUB + i) * NSUB + j] = d * ai * aa[b * NSUB + j];
    }
}

// Greedy MAP DPP (Cholesky) — one block (128 thr = 2 waves) per batch.
__global__ __launch_bounds__(128) void k_bfgm(const float* __restrict__ Lm,
                                              float* __restrict__ mu)
{
    const int b = blockIdx.x;
    const int tid = threadIdx.x;
    const float* L = Lm + (size_t)b * NSUB * NSUB;
    __shared__ float D[128], mask[128], Cm[128][MAXS], cj[MAXS];
    __shared__ float rv[2];
    __shared__ int   ri[2];
    __shared__ int   Jsh;
    const bool act = tid < NSUB;
    D[tid]    = act ? L[(size_t)tid * NSUB + tid] : 0.0f;
    mask[tid] = act ? 1.0f : 0.0f;
    #pragma unroll
    for (int k = 0; k < MAXS; ++k) Cm[tid][k] = 0.0f;
    __syncthreads();

    auto argmax_step = [&](int t) {
        float key = act ? logf(D[tid] * mask[tid]) : -INFINITY;
        if (isnan(key)) key = INFINITY;   // numpy argmax: NaN wins
        float v = key; int idx = tid;
        #pragma unroll
        for (int o = 32; o; o >>= 1) {
            float ov = __shfl_down(v, o); int oi = __shfl_down(idx, o);
            if (ov > v || (ov == v && oi < idx)) { v = ov; idx = oi; }
        }
        if ((tid & 63) == 0) { rv[tid >> 6] = v; ri[tid >> 6] = idx; }
        __syncthreads();
        if (tid == 0) {
            const int J = (rv[1] > rv[0] || (rv[1] == rv[0] && ri[1] < ri[0])) ? ri[1] : ri[0];
            Jsh = J; mask[J] = 0.0f; mu[b * MAXS + t] = (float)J;
        }
        __syncthreads();
    };

    argmax_step(0);
    for (int t = 1; t < MAXS; ++t) {
        if (tid < MAXS) cj[tid] = Cm[Jsh][tid];
        __syncthreads();
        const int J = Jsh;
        const float dj = D[J];
        float e = 0.0f;
        if (act) {
            const float Ljn = L[(size_t)J * NSUB + tid];
            float cd = 0.f;
            #pragma unroll
            for (int k = 0; k < MAXS; ++k) cd += Cm[tid][k] * cj[k];
            e = (Ljn - cd) / dj * mask[tid];
        }
        Cm[tid][t] = e;
        D[tid] -= e * e;
        __syncthreads();
        argmax_step(t);
    }
}

// dist[b,s] = softmax_s( sum_m gauss(s - mu[b,m]) ).  grid B, 256 thr
__global__ __launch_bounds__(256) void k_dist(const float* __restrict__ mu,
                                              float* __restrict__ dist)
{
    const int b = blockIdx.x;
    const int tid = threadIdx.x;
    __shared__ float mus[MAXS];
    __shared__ float w[4];
    if (tid < MAXS) mus[tid] = mu[b * MAXS + tid];
    __syncthreads();
    float g[8];
    float mx = -INFINITY;
    #pragma unroll
    for (int i = 0; i < 8; ++i) {
        const float s = (float)(tid + (i << 8));
        float acc = 0.f;
        #pragma unroll
        for (int m = 0; m < MAXS; ++m) { const float z = s - mus[m]; acc += expf(-(z * z) * INV2S2); }
        g[i] = acc * GNORM;
        mx = fmaxf(mx, g[i]);
    }
    float wm = wave_max(mx);
    if ((tid & 63) == 0) w[tid >> 6] = wm;
    __syncthreads();
    const float m = fmaxf(fmaxf(w[0], w[1]), fmaxf(w[2], w[3]));
    float sum = 0.f;
    #pragma unroll
    for (int i = 0; i < 8; ++i) { g[i] = expf(g[i] - m); sum += g[i]; }
    __syncthreads();
    float wsv = wave_sum(sum);
    if ((tid & 63) == 0) w[tid >> 6] = wsv;
    __syncthreads();
    const float inv = 1.0f / (w[0] + w[1] + w[2] + w[3]);
    #pragma unroll
    for (int i = 0; i < 8; ++i) dist[(size_t)b * SS + tid + (i << 8)] = g[i] * inv;
}

// -kl = -sum_{b,s} xm*(log(xm) - dist).  Single block.
__global__ __launch_bounds__(256) void k_kl(const float* __restrict__ xmean,
                                            const float* __restrict__ dist,
                                            float* __restrict__ outkl)
{
    const int tid = threadIdx.x;
    float acc = 0.f;
    for (int i = tid; i < BB * SS; i += 256) {
        const float xm = xmean[i];
        acc += xm * (logf(xm) - dist[i]);
    }
    __shared__ float w[4];
    float wsv = wave_sum(acc);
    if ((tid & 63) == 0) w[tid >> 6] = wsv;
    __syncthreads();
    if (tid == 0) outkl[0] = -(w[0] + w[1] + w[2] + w[3]);
}

extern "C" void kernel_launch(void* const* d_in, const int* in_sizes, int n_in,
                              void* d_out, int out_size, void* d_ws, size_t ws_size,
                              hipStream_t stream)
{
    const float* x     = (const float*)d_in[0];   // (B,T,C)
    const float* te    = (const float*)d_in[1];   // (B,T,E)
    const float* keys  = (const float*)d_in[2];   // (B,E,S)
    const float* vals  = (const float*)d_in[3];   // (B,S,E)
    const float* W_in  = (const float*)d_in[4];   // (E,C)
    const float* b_in  = (const float*)d_in[5];   // (E)
    const float* W_out = (const float*)d_in[6];   // (C,E)
    const float* b_out = (const float*)d_in[7];   // (C)

    float* outp = (float*)d_out;                       // (B,T,C)
    float* attn = outp + (size_t)BB * TT * CC;         // (B,T,S) fp32
    float* klp  = attn + (size_t)BB * TT * SS;         // scalar

    // workspace (no overlays; ~130 MB total)
    unsigned short* X       = (unsigned short*)d_ws;
    unsigned short* x_bf    = X;                                       // B*T*C
    unsigned short* Win_bf  = x_bf   + (size_t)BB * TT * CC;           // E*C
    unsigned short* Wout_bf = Win_bf + (size_t)EE * CC;                // C*E
    unsigned short* h_bf    = Wout_bf+ (size_t)CC * EE;                // B*T*E
    unsigned short* keysT   = h_bf   + (size_t)BB * TT * EE;           // B*S*E
    unsigned short* valsT   = keysT  + (size_t)BB * SS * EE;           // B*E*S
    unsigned short* attnb   = valsT  + (size_t)BB * EE * SS;           // B*T*S
    unsigned short* mid_bf  = attnb  + (size_t)BB * TT * SS;           // B*T*E
    float* fws   = (float*)(mid_bf + (size_t)BB * TT * EE + 8);
    float* xmean = fws;                                  // (B,S)
    float* ns    = xmean + (size_t)BB * SS;              // (B,N,E)
    float* aa    = ns    + (size_t)BB * NSUB * EE;       // (B,N)
    float* Lm    = aa    + (size_t)BB * NSUB;            // (B,N,N)
    float* mu    = Lm    + (size_t)BB * NSUB * NSUB;     // (B,MAXS)
    float* dist  = mu    + (size_t)BB * MAXS;            // (B,S)

    // casts
    k_cast_bf16<<<(BB * TT * CC / 4 + 255) / 256, 256, 0, stream>>>(x, x_bf, BB * TT * CC / 4);
    k_cast_bf16<<<(EE * CC / 4 + 255) / 256, 256, 0, stream>>>(W_in, Win_bf, EE * CC / 4);
    k_cast_bf16<<<(CC * EE / 4 + 255) / 256, 256, 0, stream>>>(W_out, Wout_bf, CC * EE / 4);
    // 1) h_bf = bf16((x @ W_in^T + b_in + te) * sqrt(.5))   [MODE 2]
    k_gemm_mfma<2><<<dim3(128, 2, 1), 256, 0, stream>>>(
        x_bf, Win_bf, b_in, te, nullptr, h_bf, BB * TT, CC, CC, 1.0f);
    // 2) keysT[b,s,e] = keys[b,e,s] (bf16)
    k_transpose_bf16<<<dim3(4, 32, BB), 256, 0, stream>>>(keys, keysT, EE, SS);
    // 3) scores = h @ keys  [MODE 0] -> attn region (fp32)
    k_gemm_mfma<0><<<dim3(8, 16, BB), 256, 0, stream>>>(
        h_bf, keysT, nullptr, nullptr, attn, nullptr, TT, SS, EE, 1.0f);
    // 4) valsT[b,e,s] = vals[b,s,e] (bf16)
    k_transpose_bf16<<<dim3(32, 4, BB), 256, 0, stream>>>(vals, valsT, SS, EE);
    // 5) softmax rows in place + bf16 copy
    k_softmax<<<BB * TT, 256, 0, stream>>>(attn, attnb);
    // 6) x_mean from bf16 attn
    k_xmean<<<dim3(SS / 256, BB), 256, 0, stream>>>(attnb, xmean);
    // 7) DPP chain
    k_ns<<<dim3(NSUB, BB), 256, 0, stream>>>(vals, xmean, ns, aa);
    k_L<<<dim3(NSUB, BB), 128, 0, stream>>>(ns, aa, Lm);
    k_bfgm<<<BB, 128, 0, stream>>>(Lm, mu);
    k_dist<<<BB, 256, 0, stream>>>(mu, dist);
    k_kl<<<1, 256, 0, stream>>>(xmean, dist, klp);
    // 8) mid_bf = bf16((attn @ enc_values) * sqrt(S))  [MODE 3]
    k_gemm_mfma<3><<<dim3(8, 2, BB), 256, 0, stream>>>(
        attnb, valsT, nullptr, nullptr, nullptr, mid_bf, TT, EE, SS, SQRT_S);
    // 9) out = (mid @ W_out^T + b_out + x) * sqrt(.5)  [MODE 1]
    k_gemm_mfma<1><<<dim3(128, 2, 1), 256, 0, stream>>>(
        mid_bf, Wout_bf, b_out, x, outp, nullptr, BB * TT, CC, CC, 1.0f);
}